// Round 4
// baseline (61.820 us; speedup 1.0000x reference)
//
#include <hip/hip_runtime.h>

// CRPS loss, mean reduction.
// forecasts: (N=20, M) f32 where M = B*C*D*H*W; target: (M,) f32; out: scalar f32.
// crps(m) = (1/N) sum_i |x_i - y| - (1/N^2) sum_{i<j} |x_i - x_j|
// out = mean_m crps(m)
//
// R4: grid-stride partial kernel (2048 blocks x 6 iters) -> 2048 partials,
// final single-block reduce drops from ~14us (48 serial strided loads/thread)
// to ~3us (8 coalesced loads/thread). Partial kernel unchanged otherwise:
// one dword/lane, x[20] reused per iteration (no spill; R2 lesson).

constexpr int NS = 20;          // sample count (compile-time for full unroll)
constexpr int BLOCK = 256;
constexpr int PBLOCKS = 2048;   // 8 blocks/CU on 256 CUs

__global__ __launch_bounds__(BLOCK, 8) void crps_partial_kernel(
    const float* __restrict__ forecasts,
    const float* __restrict__ target,
    float* __restrict__ partial,   // one float per block
    int M)                         // positions
{
    float local = 0.0f;
    const int stride = PBLOCKS * BLOCK;   // 524288 positions per sweep

    #pragma unroll 1                      // keep x[20] live-range per-iteration
    for (int idx = blockIdx.x * BLOCK + threadIdx.x; idx < M; idx += stride) {
        // 20 strided sample loads, one dword per lane, all issued before use.
        float x[NS];
        #pragma unroll
        for (int i = 0; i < NS; ++i)
            x[i] = forecasts[(size_t)i * (size_t)M + idx];
        const float tv = target[idx];

        float first = 0.0f;
        #pragma unroll
        for (int i = 0; i < NS; ++i)
            first += fabsf(x[i] - tv);

        float pair = 0.0f;
        #pragma unroll
        for (int i = 0; i < NS; ++i)
            #pragma unroll
            for (int j = i + 1; j < NS; ++j)
                pair += fabsf(x[i] - x[j]);

        local += first * (1.0f / NS) - pair * (1.0f / (NS * NS));
    }

    // Wave (64-lane) shuffle reduce, then cross-wave via LDS.
    #pragma unroll
    for (int off = 32; off > 0; off >>= 1)
        local += __shfl_down(local, off, 64);

    __shared__ float wsum[BLOCK / 64];
    const int lane = threadIdx.x & 63;
    const int wid  = threadIdx.x >> 6;
    if (lane == 0) wsum[wid] = local;
    __syncthreads();
    if (threadIdx.x == 0) {
        float s = 0.0f;
        #pragma unroll
        for (int w = 0; w < BLOCK / 64; ++w) s += wsum[w];
        partial[blockIdx.x] = s;
    }
}

__global__ __launch_bounds__(BLOCK) void crps_final_kernel(
    const float* __restrict__ partial,   // PBLOCKS floats
    float* __restrict__ out,
    float invM)
{
    // 8 coalesced loads per thread, fixed order -> deterministic.
    float s = 0.0f;
    #pragma unroll
    for (int k = 0; k < PBLOCKS / BLOCK; ++k)
        s += partial[k * BLOCK + threadIdx.x];

    #pragma unroll
    for (int off = 32; off > 0; off >>= 1)
        s += __shfl_down(s, off, 64);

    __shared__ float wsum[BLOCK / 64];
    const int lane = threadIdx.x & 63;
    const int wid  = threadIdx.x >> 6;
    if (lane == 0) wsum[wid] = s;
    __syncthreads();
    if (threadIdx.x == 0) {
        float tot = 0.0f;
        #pragma unroll
        for (int w = 0; w < BLOCK / 64; ++w) tot += wsum[w];
        out[0] = tot * invM;
    }
}

extern "C" void kernel_launch(void* const* d_in, const int* in_sizes, int n_in,
                              void* d_out, int out_size, void* d_ws, size_t ws_size,
                              hipStream_t stream) {
    const float* forecasts = (const float*)d_in[0];
    const float* target    = (const float*)d_in[1];
    float* out = (float*)d_out;
    float* partial = (float*)d_ws;

    const int M = in_sizes[1];           // B*C*D*H*W = 3,145,728

    crps_partial_kernel<<<PBLOCKS, BLOCK, 0, stream>>>(forecasts, target, partial, M);
    crps_final_kernel<<<1, BLOCK, 0, stream>>>(partial, out, 1.0f / (float)M);
}

// Round 5
// 47.732 us; speedup vs baseline: 1.2951x; 1.2951x over previous
//
#include <hip/hip_runtime.h>

// CRPS loss, mean reduction.
// forecasts: (N=20, M) f32 where M = B*C*D*H*W; target: (M,) f32; out: scalar f32.
// crps(m) = (1/N) sum_i |x_i - y| - (1/N^2) sum_{i<j} |x_i - x_j|
// out = mean_m crps(m)
//
// R5: R4 + nontemporal loads. Working set (264.3 MB) is 103% of the 256 MiB
// Infinity Cache -> every replay thrashes L3 (allocate+evict with zero reuse).
// nt loads skip cache allocation and stream straight from HBM.
// (R1 float4/5-waves == R3 dword/8-waves == ~4.6 TB/s showed width and
// occupancy are not the limiter; cache policy is the remaining axis.)

constexpr int NS = 20;          // sample count (compile-time for full unroll)
constexpr int BLOCK = 256;
constexpr int PBLOCKS = 2048;   // 8 blocks/CU on 256 CUs

__global__ __launch_bounds__(BLOCK, 8) void crps_partial_kernel(
    const float* __restrict__ forecasts,
    const float* __restrict__ target,
    float* __restrict__ partial,   // one float per block
    int M)                         // positions
{
    float local = 0.0f;
    const int stride = PBLOCKS * BLOCK;   // 524288 positions per sweep

    #pragma unroll 1                      // keep x[20] live-range per-iteration
    for (int idx = blockIdx.x * BLOCK + threadIdx.x; idx < M; idx += stride) {
        // 20 strided sample loads, one dword per lane, streaming (nt):
        // read-once data, do not allocate in L2/L3.
        float x[NS];
        #pragma unroll
        for (int i = 0; i < NS; ++i)
            x[i] = __builtin_nontemporal_load(&forecasts[(size_t)i * (size_t)M + idx]);
        const float tv = __builtin_nontemporal_load(&target[idx]);

        float first = 0.0f;
        #pragma unroll
        for (int i = 0; i < NS; ++i)
            first += fabsf(x[i] - tv);

        float pair = 0.0f;
        #pragma unroll
        for (int i = 0; i < NS; ++i)
            #pragma unroll
            for (int j = i + 1; j < NS; ++j)
                pair += fabsf(x[i] - x[j]);

        local += first * (1.0f / NS) - pair * (1.0f / (NS * NS));
    }

    // Wave (64-lane) shuffle reduce, then cross-wave via LDS.
    #pragma unroll
    for (int off = 32; off > 0; off >>= 1)
        local += __shfl_down(local, off, 64);

    __shared__ float wsum[BLOCK / 64];
    const int lane = threadIdx.x & 63;
    const int wid  = threadIdx.x >> 6;
    if (lane == 0) wsum[wid] = local;
    __syncthreads();
    if (threadIdx.x == 0) {
        float s = 0.0f;
        #pragma unroll
        for (int w = 0; w < BLOCK / 64; ++w) s += wsum[w];
        partial[blockIdx.x] = s;
    }
}

__global__ __launch_bounds__(BLOCK) void crps_final_kernel(
    const float* __restrict__ partial,   // PBLOCKS floats
    float* __restrict__ out,
    float invM)
{
    // 8 coalesced loads per thread, fixed order -> deterministic.
    float s = 0.0f;
    #pragma unroll
    for (int k = 0; k < PBLOCKS / BLOCK; ++k)
        s += partial[k * BLOCK + threadIdx.x];

    #pragma unroll
    for (int off = 32; off > 0; off >>= 1)
        s += __shfl_down(s, off, 64);

    __shared__ float wsum[BLOCK / 64];
    const int lane = threadIdx.x & 63;
    const int wid  = threadIdx.x >> 6;
    if (lane == 0) wsum[wid] = s;
    __syncthreads();
    if (threadIdx.x == 0) {
        float tot = 0.0f;
        #pragma unroll
        for (int w = 0; w < BLOCK / 64; ++w) tot += wsum[w];
        out[0] = tot * invM;
    }
}

extern "C" void kernel_launch(void* const* d_in, const int* in_sizes, int n_in,
                              void* d_out, int out_size, void* d_ws, size_t ws_size,
                              hipStream_t stream) {
    const float* forecasts = (const float*)d_in[0];
    const float* target    = (const float*)d_in[1];
    float* out = (float*)d_out;
    float* partial = (float*)d_ws;

    const int M = in_sizes[1];           // B*C*D*H*W = 3,145,728

    crps_partial_kernel<<<PBLOCKS, BLOCK, 0, stream>>>(forecasts, target, partial, M);
    crps_final_kernel<<<1, BLOCK, 0, stream>>>(partial, out, 1.0f / (float)M);
}